// Round 3
// 497.638 us; speedup vs baseline: 1.0219x; 1.0219x over previous
//
#include <hip/hip_runtime.h>
#include <stdint.h>

// ---------------------------------------------------------------------------
// Qwen2 MoE sparse block, MI355X/gfx950.  FP32 I/O, bf16 MFMA internally.
// T=2048, D=2048, E=8, F=1408, top-2.  Sparse dispatch (~71 GFLOP vs 283).
// Round 10: fix tr_read lane addressing (round-8/9 had column step = 2B,
// correct is 8B: lane byte addr A -> block A&~127, column (A>>3)&15, rows
// j=0..3 delivered; derived from m156/m162 measured layout).
//   - transpose_* -> layout-preserving fp32->bf16 convert (pure stream).
//   - GEMM B-tiles staged via gld16 with PRE-SWIZZLED global source into a
//     [k/4][f/16] chunked LDS layout; fragments read with ds_read_b64_tr_b16.
// ---------------------------------------------------------------------------

#define TT 2048
#define DD 2048
#define FF 1408
#define NE 8
#define HROWS 5120          // >= sum of per-expert counts padded to 128 (<=5112)
#define TRASH (2*TT)        // Y trash row for pad entries

typedef float f32x4 __attribute__((ext_vector_type(4)));
typedef short bf16x8 __attribute__((ext_vector_type(8)));
typedef short bf16x4 __attribute__((ext_vector_type(4)));
typedef const __attribute__((address_space(3))) unsigned short* lds_cp;

__device__ __forceinline__ unsigned short f2bf(float f) {
    unsigned int x = __float_as_uint(f);
    return (unsigned short)((x + 0x7fffu + ((x >> 16) & 1u)) >> 16);
}
__device__ __forceinline__ float bf2f(unsigned short u) {
    union { unsigned int i; float f; } v; v.i = ((unsigned int)u) << 16; return v.f;
}
__device__ __forceinline__ void gld16(const void* g, void* l) {
    __builtin_amdgcn_global_load_lds((const __attribute__((address_space(1))) void*)g,
                                     (__attribute__((address_space(3))) void*)l, 16, 0, 0);
}

// HW transpose read: lane byte addr A -> 128B block (A&~127), column (A>>3)&15;
// lane receives that column's rows j=0..3 of the [4][16] bf16 block.
#define TR16(d, p, imm) \
    asm volatile("ds_read_b64_tr_b16 %0, %1 offset:" imm : "=&v"(d) : "v"(p))

// ---------------------------------------------------------------------------
// Layout-preserving fp32 -> bf16 converts (replace the strided transposes).
// Fully coalesced both sides: 32B/lane read, 16B/lane write.
// ---------------------------------------------------------------------------
__global__ void convert_gu_kernel(const float* __restrict__ wg,
                                  const float* __restrict__ wu,
                                  unsigned short* __restrict__ G,
                                  unsigned short* __restrict__ U) {
    const int z = blockIdx.z;
    const float* s; unsigned short* d;
    if (z < NE) { s = wg + (size_t)z * DD * FF;        d = G + (size_t)z * DD * FF; }
    else        { s = wu + (size_t)(z - NE) * DD * FF; d = U + (size_t)(z - NE) * DD * FF; }
    const size_t i = ((size_t)blockIdx.x * 256 + threadIdx.x) * 8;
    float4 a = *(const float4*)(s + i);
    float4 b = *(const float4*)(s + i + 4);
    uint4 o; unsigned short* po = (unsigned short*)&o;
    po[0] = f2bf(a.x); po[1] = f2bf(a.y); po[2] = f2bf(a.z); po[3] = f2bf(a.w);
    po[4] = f2bf(b.x); po[5] = f2bf(b.y); po[6] = f2bf(b.z); po[7] = f2bf(b.w);
    *(uint4*)(d + i) = o;
}

__global__ void convert_d_kernel(const float* __restrict__ wd,
                                 unsigned short* __restrict__ W) {
    const int z = blockIdx.z;
    const float* s = wd + (size_t)z * FF * DD;
    unsigned short* d = W + (size_t)z * FF * DD;
    const size_t i = ((size_t)blockIdx.x * 256 + threadIdx.x) * 8;
    float4 a = *(const float4*)(s + i);
    float4 b = *(const float4*)(s + i + 4);
    uint4 o; unsigned short* po = (unsigned short*)&o;
    po[0] = f2bf(a.x); po[1] = f2bf(a.y); po[2] = f2bf(a.z); po[3] = f2bf(a.w);
    po[4] = f2bf(b.x); po[5] = f2bf(b.y); po[6] = f2bf(b.z); po[7] = f2bf(b.w);
    *(uint4*)(d + i) = o;
}

// ---------------------------------------------------------------------------
// Router (wave/token, fp32) + X->bf16 emit + fused finalize (last block).
// ---------------------------------------------------------------------------
__global__ void router_kernel(const float* __restrict__ x,
                              const float* __restrict__ gw,
                              int* __restrict__ cnt,        // [NE+1], cnt[NE]=done
                              int* __restrict__ tok,
                              float* __restrict__ wtv,
                              int* __restrict__ dstv,
                              unsigned short* __restrict__ xb,
                              int* __restrict__ basep,
                              int* __restrict__ cntpad) {
    __shared__ int s_last;
    __shared__ int sc[NE], sp[NE];

    const int wv = threadIdx.x >> 6, lane = threadIdx.x & 63;
    const int t = blockIdx.x * 4 + wv;
    float acc[NE];
#pragma unroll
    for (int e = 0; e < NE; ++e) acc[e] = 0.f;
    const float* xr = x + (size_t)t * DD;
    unsigned short* xbr = xb + (size_t)t * DD;
#pragma unroll
    for (int it = 0; it < DD / 256; ++it) {
        const int j = it * 256 + lane * 4;
        float4 xv = *(const float4*)(xr + j);
        short4 o;
        o.x = (short)f2bf(xv.x); o.y = (short)f2bf(xv.y);
        o.z = (short)f2bf(xv.z); o.w = (short)f2bf(xv.w);
        *(short4*)(xbr + j) = o;
#pragma unroll
        for (int e = 0; e < NE; ++e) {
            float4 g = *(const float4*)(gw + e * DD + j);
            acc[e] += xv.x * g.x + xv.y * g.y + xv.z * g.z + xv.w * g.w;
        }
    }
#pragma unroll
    for (int e = 0; e < NE; ++e) {
        float v = acc[e];
        v += __shfl_xor(v, 32); v += __shfl_xor(v, 16); v += __shfl_xor(v, 8);
        v += __shfl_xor(v, 4);  v += __shfl_xor(v, 2);  v += __shfl_xor(v, 1);
        acc[e] = v;
    }
    if (lane == 0) {
        float mx = acc[0];
#pragma unroll
        for (int e = 1; e < NE; ++e) mx = fmaxf(mx, acc[e]);
        float p[NE], s = 0.f;
#pragma unroll
        for (int e = 0; e < NE; ++e) { p[e] = __expf(acc[e] - mx); s += p[e]; }
        int i0 = 0;
#pragma unroll
        for (int e = 1; e < NE; ++e) if (p[e] > p[i0]) i0 = e;
        int i1 = (i0 == 0) ? 1 : 0;
#pragma unroll
        for (int e = 0; e < NE; ++e) if (e != i0 && p[e] > p[i1]) i1 = e;
        float inv = 1.f / s;
        int p0 = atomicAdd(&cnt[i0], 1);
        tok[i0 * TT + p0] = t; wtv[i0 * TT + p0] = p[i0] * inv; dstv[i0 * TT + p0] = 2 * t;
        int p1 = atomicAdd(&cnt[i1], 1);
        tok[i1 * TT + p1] = t; wtv[i1 * TT + p1] = p[i1] * inv; dstv[i1 * TT + p1] = 2 * t + 1;
    }

    __syncthreads();
    if (threadIdx.x == 0) {
        __threadfence();
        int d = atomicAdd(&cnt[NE], 1);
        s_last = (d == (TT / 4) - 1) ? 1 : 0;
    }
    __syncthreads();
    if (s_last) {
        if (threadIdx.x == 0) {
            int b = 0;
            for (int e = 0; e < NE; ++e) {
                int c = atomicAdd(&cnt[e], 0);
                int pd = (c + 127) & ~127;
                basep[e] = b; cntpad[e] = pd; sc[e] = c; sp[e] = pd; b += pd;
            }
        }
        __syncthreads();
        for (int e = 0; e < NE; ++e)
            for (int i = sc[e] + (int)threadIdx.x; i < sp[e]; i += 256) {
                tok[e * TT + i] = 0; wtv[e * TT + i] = 0.f; dstv[e * TT + i] = TRASH;
            }
    }
}

// ---------------------------------------------------------------------------
// B-tile source swizzle: LDS 16B slot s (0..511) of the chunked layout
//   chunk(kc=k>>2, fc=f>>4) at (kc*8+fc)*64 shorts, within (k&3)*16 + (f&15)
// maps to global (k, f) = (4*(s>>6) + ((s>>1)&3), 16*((s>>3)&7) + 8*(s&1)),
// which is 8 f-contiguous shorts -> one clean 16B global read per lane.
// ---------------------------------------------------------------------------

// ---------------------------------------------------------------------------
// GEMM1 fused gate+up+silu*mul.  128M x (128g + 128u)N tile, BK=32, 4 waves
// (2x2 of 64x64), gld16 staging (6/thread/iter), tr_b16 B-fragments.
// ---------------------------------------------------------------------------
__launch_bounds__(256, 2)
__global__ void gemm1_kernel(const unsigned short* __restrict__ Xb,
                             const unsigned short* __restrict__ Wg,
                             const unsigned short* __restrict__ Wu,
                             const int* __restrict__ tok,
                             const int* __restrict__ base,
                             const int* __restrict__ cntpad,
                             unsigned short* __restrict__ H) {
    __shared__ unsigned short As[128 * 32];
    __shared__ unsigned short Bg[128 * 32];
    __shared__ unsigned short Bu[128 * 32];
    __shared__ int s_tok[128];

    const int e = blockIdx.z, rb = blockIdx.y, fb = blockIdx.x;
    const int cp = cntpad[e];
    if (rb * 128 >= cp) return;
    const int b0 = base[e];

    const int tid = threadIdx.x;
    if (tid < 128) s_tok[tid] = tok[e * TT + rb * 128 + tid];
    __syncthreads();

    const int w = tid >> 6, lane = tid & 63;
    const int r = lane & 15, q = lane >> 4;
    const int wm = w & 1, wn = w >> 1;

    // A staging: linear [row][32k] (rows are k-contiguous in Xb).
    const int srow = w * 32 + (lane >> 2);
    const int koff = (lane & 3) * 8;
    const unsigned short* ga0 = Xb + (size_t)s_tok[srow] * DD + koff;
    const unsigned short* ga1 = Xb + (size_t)s_tok[srow + 16] * DD + koff;
    unsigned short* la0 = As + srow * 32 + koff;
    unsigned short* la1 = la0 + 512;

    // B staging: chunked LDS layout via pre-swizzled global source.
    const int s0 = tid, s1 = tid + 256;
    const int k0 = 4 * (s0 >> 6) + ((s0 >> 1) & 3), f0 = 16 * ((s0 >> 3) & 7) + 8 * (s0 & 1);
    const int k1 = 4 * (s1 >> 6) + ((s1 >> 1) & 3), f1 = 16 * ((s1 >> 3) & 7) + 8 * (s1 & 1);
    const size_t wb = (size_t)e * DD * FF + (size_t)fb * 128;
    const unsigned short* gg0 = Wg + wb + (size_t)k0 * FF + f0;
    const unsigned short* gg1 = Wg + wb + (size_t)k1 * FF + f1;
    const unsigned short* gu0 = Wu + wb + (size_t)k0 * FF + f0;
    const unsigned short* gu1 = Wu + wb + (size_t)k1 * FF + f1;
    unsigned short* lg0 = Bg + s0 * 8;
    unsigned short* lg1 = Bg + s1 * 8;
    unsigned short* lu0 = Bu + s0 * 8;
    unsigned short* lu1 = Bu + s1 * 8;

    // tr_read lane base: chunk (2q, wn*4) byte base q*2048 + wn*512, column r
    // at +8*r bytes -> shorts: q*1024 + wn*256 + 4*r.
    lds_cp bg = (lds_cp)Bg + (q * 1024 + wn * 256 + 4 * r);
    lds_cp bu = (lds_cp)Bu + (q * 1024 + wn * 256 + 4 * r);

    f32x4 accg[4][4] = {};
    f32x4 accu[4][4] = {};

    for (int kt = 0; kt < DD / 32; ++kt) {
        gld16(ga0, la0); gld16(ga1, la1);
        gld16(gg0, lg0); gld16(gg1, lg1);
        gld16(gu0, lu0); gld16(gu1, lu1);
        ga0 += 32; ga1 += 32;
        gg0 += 32 * FF; gg1 += 32 * FF; gu0 += 32 * FF; gu1 += 32 * FF;
        __syncthreads();

        bf16x8 af[4];
#pragma unroll
        for (int m = 0; m < 4; ++m)
            af[m] = *(const bf16x8*)&As[(wm * 64 + m * 16 + r) * 32 + q * 8];

        // B fragments: per n, chunks (2q, 4wn+n) and (2q+1, 4wn+n):
        // byte off = n*128 and 1024 + n*128 from lane base.
        bf16x4 gA[8], uA[8];
        TR16(gA[0], bg, "0");    TR16(gA[1], bg, "1024");
        TR16(gA[2], bg, "128");  TR16(gA[3], bg, "1152");
        TR16(gA[4], bg, "256");  TR16(gA[5], bg, "1280");
        TR16(gA[6], bg, "384");  TR16(gA[7], bg, "1408");
        TR16(uA[0], bu, "0");    TR16(uA[1], bu, "1024");
        TR16(uA[2], bu, "128");  TR16(uA[3], bu, "1152");
        TR16(uA[4], bu, "256");  TR16(uA[5], bu, "1280");
        TR16(uA[6], bu, "384");  TR16(uA[7], bu, "1408");
        asm volatile("s_waitcnt lgkmcnt(0)" ::: "memory");
        __builtin_amdgcn_sched_barrier(0);

        bf16x8 gf[4], uf[4];
#pragma unroll
        for (int n = 0; n < 4; ++n) {
            gf[n] = __builtin_shufflevector(gA[2 * n], gA[2 * n + 1], 0, 1, 2, 3, 4, 5, 6, 7);
            uf[n] = __builtin_shufflevector(uA[2 * n], uA[2 * n + 1], 0, 1, 2, 3, 4, 5, 6, 7);
        }
#pragma unroll
        for (int m = 0; m < 4; ++m)
#pragma unroll
            for (int n = 0; n < 4; ++n) {
                accg[m][n] = __builtin_amdgcn_mfma_f32_16x16x32_bf16(af[m], gf[n], accg[m][n], 0, 0, 0);
                accu[m][n] = __builtin_amdgcn_mfma_f32_16x16x32_bf16(af[m], uf[n], accu[m][n], 0, 0, 0);
            }
        __syncthreads();
    }

    const size_t hr0 = (size_t)(b0 + rb * 128 + wm * 64);
#pragma unroll
    for (int m = 0; m < 4; ++m)
#pragma unroll
        for (int n = 0; n < 4; ++n)
#pragma unroll
            for (int rr = 0; rr < 4; ++rr) {
                float g = accg[m][n][rr], u = accu[m][n][rr];
                float h = (g / (1.f + __expf(-g))) * u;      // silu(g)*u
                int row = m * 16 + q * 4 + rr;
                int col = fb * 128 + wn * 64 + n * 16 + r;
                H[(hr0 + row) * FF + col] = f2bf(h);
            }
}

// ---------------------------------------------------------------------------
// GEMM2: Y[dst,d] = w * (H_row . Wd[:,d]).  128x128, BK=32, gld16 + tr_b16.
// Wd layout [e][F][D]: k rows of F, cols of D.
// ---------------------------------------------------------------------------
__launch_bounds__(256, 2)
__global__ void gemm2_kernel(const unsigned short* __restrict__ H,
                             const unsigned short* __restrict__ Wd,
                             const float* __restrict__ wtv,
                             const int* __restrict__ dstv,
                             const int* __restrict__ base,
                             const int* __restrict__ cntpad,
                             unsigned short* __restrict__ Y) {
    __shared__ unsigned short As[128 * 32];
    __shared__ unsigned short Bs[128 * 32];
    __shared__ float s_w[128];
    __shared__ int s_d[128];

    const int e = blockIdx.z, rb = blockIdx.y, db = blockIdx.x;   // db 0..15
    const int cp = cntpad[e];
    if (rb * 128 >= cp) return;
    const int b0 = base[e];

    const int tid = threadIdx.x;
    if (tid < 128) {
        int idx = e * TT + rb * 128 + tid;
        s_w[tid] = wtv[idx]; s_d[tid] = dstv[idx];
    }
    __syncthreads();

    const int w = tid >> 6, lane = tid & 63;
    const int r = lane & 15, q = lane >> 4;
    const int wm = w & 1, wn = w >> 1;

    const int srow = w * 32 + (lane >> 2);
    const int koff = (lane & 3) * 8;
    const unsigned short* ga0 = H + (size_t)(b0 + rb * 128 + srow) * FF + koff;
    const unsigned short* ga1 = ga0 + (size_t)16 * FF;
    unsigned short* la0 = As + srow * 32 + koff;
    unsigned short* la1 = la0 + 512;

    const int s0 = tid, s1 = tid + 256;
    const int k0 = 4 * (s0 >> 6) + ((s0 >> 1) & 3), f0 = 16 * ((s0 >> 3) & 7) + 8 * (s0 & 1);
    const int k1 = 4 * (s1 >> 6) + ((s1 >> 1) & 3), f1 = 16 * ((s1 >> 3) & 7) + 8 * (s1 & 1);
    const size_t wb = (size_t)e * FF * DD + (size_t)db * 128;
    const unsigned short* gb0 = Wd + wb + (size_t)k0 * DD + f0;
    const unsigned short* gb1 = Wd + wb + (size_t)k1 * DD + f1;
    unsigned short* lb0 = Bs + s0 * 8;
    unsigned short* lb1 = Bs + s1 * 8;

    lds_cp bb = (lds_cp)Bs + (q * 1024 + wn * 256 + 4 * r);

    f32x4 acc[4][4] = {};

    for (int kt = 0; kt < FF / 32; ++kt) {
        gld16(ga0, la0); gld16(ga1, la1);
        gld16(gb0, lb0); gld16(gb1, lb1);
        ga0 += 32; ga1 += 32;
        gb0 += 32 * DD; gb1 += 32 * DD;
        __syncthreads();

        bf16x8 af[4];
#pragma unroll
        for (int m = 0; m < 4; ++m)
            af[m] = *(const bf16x8*)&As[(wm * 64 + m * 16 + r) * 32 + q * 8];

        bf16x4 bA[8];
        TR16(bA[0], bb, "0");    TR16(bA[1], bb, "1024");
        TR16(bA[2], bb, "128");  TR16(bA[3], bb, "1152");
        TR16(bA[4], bb, "256");  TR16(bA[5], bb, "1280");
        TR16(bA[6], bb, "384");  TR16(bA[7], bb, "1408");
        asm volatile("s_waitcnt lgkmcnt(0)" ::: "memory");
        __builtin_amdgcn_sched_barrier(0);

        bf16x8 bf[4];
#pragma unroll
        for (int n = 0; n < 4; ++n)
            bf[n] = __builtin_shufflevector(bA[2 * n], bA[2 * n + 1], 0, 1, 2, 3, 4, 5, 6, 7);
#pragma unroll
        for (int m = 0; m < 4; ++m)
#pragma unroll
            for (int n = 0; n < 4; ++n)
                acc[m][n] = __builtin_amdgcn_mfma_f32_16x16x32_bf16(af[m], bf[n], acc[m][n], 0, 0, 0);
        __syncthreads();
    }

#pragma unroll
    for (int m = 0; m < 4; ++m)
#pragma unroll
        for (int n = 0; n < 4; ++n)
#pragma unroll
            for (int rr = 0; rr < 4; ++rr) {
                int row = wm * 64 + m * 16 + q * 4 + rr;
                int col = db * 128 + wn * 64 + n * 16 + r;
                float v = s_w[row] * acc[m][n][rr];
                Y[(size_t)s_d[row] * DD + col] = f2bf(v);
            }
}

// ---------------------------------------------------------------------------
// Combine: out[t,d] = Y[2t,d] + Y[2t+1,d]  -> fp32 out.
// ---------------------------------------------------------------------------
__global__ void combine_kernel(const unsigned short* __restrict__ Y,
                               float* __restrict__ out) {
    const int t = blockIdx.x;
    const int d = threadIdx.x * 8;
    uint4 a = *(const uint4*)(Y + (size_t)(2 * t) * DD + d);
    uint4 b = *(const uint4*)(Y + (size_t)(2 * t + 1) * DD + d);
    const unsigned short* pa = (const unsigned short*)&a;
    const unsigned short* pb = (const unsigned short*)&b;
    float4 o0, o1;
    o0.x = bf2f(pa[0]) + bf2f(pb[0]);  o0.y = bf2f(pa[1]) + bf2f(pb[1]);
    o0.z = bf2f(pa[2]) + bf2f(pb[2]);  o0.w = bf2f(pa[3]) + bf2f(pb[3]);
    o1.x = bf2f(pa[4]) + bf2f(pb[4]);  o1.y = bf2f(pa[5]) + bf2f(pb[5]);
    o1.z = bf2f(pa[6]) + bf2f(pb[6]);  o1.w = bf2f(pa[7]) + bf2f(pb[7]);
    float* op = out + (size_t)t * DD + d;
    ((float4*)op)[0] = o0;
    ((float4*)op)[1] = o1;
}

// ---------------------------------------------------------------------------
extern "C" void kernel_launch(void* const* d_in, const int* in_sizes, int n_in,
                              void* d_out, int out_size, void* d_ws, size_t ws_size,
                              hipStream_t stream) {
    const float* x      = (const float*)d_in[0];
    const float* gw     = (const float*)d_in[1];
    const float* w_gate = (const float*)d_in[2];
    const float* w_up   = (const float*)d_in[3];
    const float* w_down = (const float*)d_in[4];
    float* out = (float*)d_out;

    uint8_t* ws = (uint8_t*)d_ws;
    size_t off = 0;
    auto alloc = [&](size_t bytes) -> void* {
        void* p = ws + off;
        off = (off + bytes + 255) & ~(size_t)255;
        return p;
    };
    int*   cnt    = (int*)  alloc((NE + 1) * 4);
    int*   basep  = (int*)  alloc(NE * 4);
    int*   cntpad = (int*)  alloc(NE * 4);
    int*   tok    = (int*)  alloc((size_t)NE * TT * 4);
    float* wtv    = (float*)alloc((size_t)NE * TT * 4);
    int*   dstv   = (int*)  alloc((size_t)NE * TT * 4);
    unsigned short* Xb  = (unsigned short*)alloc((size_t)TT * DD * 2);
    unsigned short* Hb  = (unsigned short*)alloc((size_t)HROWS * FF * 2);
    unsigned short* Yb  = (unsigned short*)alloc((size_t)(2 * TT + 8) * DD * 2);
    // Reused region: WgB+WuB (bf16) for gemm1, then WdB aliases WgB for gemm2.
    unsigned short* WT  = (unsigned short*)alloc((size_t)2 * NE * FF * DD * 2);
    unsigned short* WgB = WT;
    unsigned short* WuB = WT + (size_t)NE * FF * DD;
    unsigned short* WdB = WT;
    (void)ws_size; (void)in_sizes; (void)n_in; (void)out_size;

    hipMemsetAsync(cnt, 0, (NE + 1) * 4, stream);
    convert_gu_kernel<<<dim3(DD * FF / 2048, 1, 2 * NE), 256, 0, stream>>>(w_gate, w_up, WgB, WuB);
    router_kernel<<<dim3(TT / 4), 256, 0, stream>>>(x, gw, cnt, tok, wtv, dstv, Xb, basep, cntpad);
    gemm1_kernel<<<dim3(FF / 128, TT / 128, NE), 256, 0, stream>>>(Xb, WgB, WuB, tok, basep, cntpad, Hb);
    convert_d_kernel<<<dim3(FF * DD / 2048, 1, NE), 256, 0, stream>>>(w_down, WdB);
    gemm2_kernel<<<dim3(DD / 128, TT / 128, NE), 256, 0, stream>>>(Hb, WdB, wtv, dstv, basep, cntpad, Yb);
    combine_kernel<<<dim3(TT), 256, 0, stream>>>(Yb, out);
}